// Round 7
// baseline (568.829 us; speedup 1.0000x reference)
//
#include <hip/hip_runtime.h>

#define TT 8192      // tokens = B*S
#define HD 1024      // hidden
#define ID 2816      // intermediate
#define NE 8         // experts

typedef unsigned short u16;
typedef __attribute__((ext_vector_type(8))) __bf16 bf16x8;
typedef __attribute__((ext_vector_type(4))) float f32x4;

static constexpr int BM = 128;
static constexpr int BK = 64;
static constexpr int MAXSLOT = 17408;   // 136 tiles * 128 rows (16384 + worst-case pad)
static constexpr int MTILES  = 136;
static constexpr int NN1     = ID/BM;   // 22 n-tiles in gemm1
static constexpr int G1      = MTILES*NN1;   // 2992 = 8*374, band 8m*22n=176, 17 bands
static constexpr int G2      = MTILES*8*2;   // 2176 = 8*272; kh halves of 1088; band 8m*8n=64, 17 bands
static constexpr int RTR_BLK = 256;          // router compute blocks
static constexpr int RTR_CVT = 1024;         // fused Wg/Wu cvt blocks in router
static constexpr int G1_CVT  = 512;          // fused Wd cvt blocks in gemm1

struct Meta {
  u16   zeros[32];   // 64B zero page, 16B aligned (struct offset 0)
  int   cnt[NE];
  float psum[NE];
  int   cursor[NE];
  int   seg[12];     // seg[0..8] used (padded segment starts)
};

// workspace layout (all 16B-aligned)
static constexpr size_t OFF_XH    = 0;
static constexpr size_t OFF_WGH   = OFF_XH   + (size_t)TT*HD*2;
static constexpr size_t OFF_WUH   = OFF_WGH  + (size_t)NE*ID*HD*2;
static constexpr size_t OFF_WDH   = OFF_WUH  + (size_t)NE*ID*HD*2;
static constexpr size_t OFF_ACT   = OFF_WDH  + (size_t)NE*HD*ID*2;
static constexpr size_t OFF_PERM  = OFF_ACT  + (size_t)MAXSLOT*ID*2;
static constexpr size_t OFF_TID   = OFF_PERM + (size_t)MAXSLOT*4;
static constexpr size_t OFF_TSLOT = OFF_TID  + (size_t)TT*2*4;
static constexpr size_t OFF_TW    = OFF_TSLOT+ (size_t)TT*2*4;
static constexpr size_t OFF_META  = OFF_TW   + (size_t)TT*2*4;
static constexpr size_t WS_NEED   = OFF_META + sizeof(Meta);
// y: 2 bf16 K-half buffers [2][MAXSLOT][HD] (71.3 MB) overlay WGH+WUH (92.4 MB, dead after gemm1)
static constexpr size_t OFF_Y     = OFF_WGH;

__device__ __forceinline__ u16 f2bf(float f) {
  unsigned u = __float_as_uint(f);
  u += 0x7FFFu + ((u >> 16) & 1u);   // RNE
  return (u16)(u >> 16);
}
__device__ __forceinline__ float bf2f(u16 h) {
  return __uint_as_float(((unsigned)h) << 16);
}

__device__ __forceinline__ float dot4(float4 a, float4 b) {
  return a.x*b.x + a.y*b.y + a.z*b.z + a.w*b.w;
}

__device__ __forceinline__ void gll16(const void* g, void* l) {
  __builtin_amdgcn_global_load_lds(
      (const __attribute__((address_space(1))) void*)g,
      (__attribute__((address_space(3))) void*)l, 16, 0, 0);
}

__device__ __forceinline__ void cvt8(const float* __restrict__ src, u16* __restrict__ dst) {
  const float4* s4 = (const float4*)src;
  float4 a = s4[0], b = s4[1];
  union { u16 h[8]; uint4 v; } r;
  r.h[0]=f2bf(a.x); r.h[1]=f2bf(a.y); r.h[2]=f2bf(a.z); r.h[3]=f2bf(a.w);
  r.h[4]=f2bf(b.x); r.h[5]=f2bf(b.y); r.h[6]=f2bf(b.z); r.h[7]=f2bf(b.w);
  *(uint4*)dst = r.v;
}

__global__ void k_init(int* __restrict__ perm, Meta* __restrict__ meta) {
  int gid  = blockIdx.x*blockDim.x + threadIdx.x;
  int nthr = gridDim.x*blockDim.x;
  for (int i = gid; i < MAXSLOT; i += nthr) perm[i] = -1;
  if (gid < 32) meta->zeros[gid] = 0;
  if (gid < NE) { meta->cnt[gid]=0; meta->psum[gid]=0.f; meta->cursor[gid]=0; }
}

// one wave per token; fp32 logits to match reference top-k selection.
// Emits xh (bf16 x). Blocks >= RTR_BLK instead convert Wg|Wu -> wgh|wuh
// (contiguous dst), hiding that BW work under the router's latency-bound
// phase; gemm1 (the consumer) launches only after this kernel completes.
__global__ void k_router(const float* __restrict__ x, const float* __restrict__ gw,
                         int* __restrict__ tke, float* __restrict__ tkw,
                         u16* __restrict__ xh, Meta* __restrict__ meta,
                         const float* __restrict__ Wg, const float* __restrict__ Wu,
                         u16* __restrict__ wgh) {
  if (blockIdx.x >= RTR_BLK) {
    const long per = (long)NE*ID*HD/8;
    long base = (long)(blockIdx.x - RTR_BLK)*256 + threadIdx.x;
    for (long idx = base; idx < 2*per; idx += (long)RTR_CVT*256) {
      const float* src = (idx < per) ? (Wg + idx*8) : (Wu + (idx-per)*8);
      cvt8(src, wgh + idx*8);
    }
    return;
  }
  __shared__ int   s_cnt[NE];
  __shared__ float s_ps[NE];
  int tid = threadIdx.x;
  if (tid < NE) { s_cnt[tid]=0; s_ps[tid]=0.f; }
  __syncthreads();
  int wv = tid>>6, ln = tid&63;
  for (int it = 0; it < 8; ++it) {
    int t = it*1024 + blockIdx.x*4 + wv;
    const float4* xp = (const float4*)(x + (size_t)t*HD + ln*16);
    float4 xv0=xp[0], xv1=xp[1], xv2=xp[2], xv3=xp[3];
    // bf16 copy
    union { u16 h[8]; uint4 v; } r0, r1;
    r0.h[0]=f2bf(xv0.x); r0.h[1]=f2bf(xv0.y); r0.h[2]=f2bf(xv0.z); r0.h[3]=f2bf(xv0.w);
    r0.h[4]=f2bf(xv1.x); r0.h[5]=f2bf(xv1.y); r0.h[6]=f2bf(xv1.z); r0.h[7]=f2bf(xv1.w);
    r1.h[0]=f2bf(xv2.x); r1.h[1]=f2bf(xv2.y); r1.h[2]=f2bf(xv2.z); r1.h[3]=f2bf(xv2.w);
    r1.h[4]=f2bf(xv3.x); r1.h[5]=f2bf(xv3.y); r1.h[6]=f2bf(xv3.z); r1.h[7]=f2bf(xv3.w);
    uint4* xo = (uint4*)(xh + (size_t)t*HD + ln*16);
    xo[0] = r0.v; xo[1] = r1.v;
    float lg[NE];
    #pragma unroll
    for (int e=0;e<NE;++e) {
      const float4* gp = (const float4*)(gw + e*HD + ln*16);
      lg[e] = dot4(xv0,gp[0]) + dot4(xv1,gp[1]) + dot4(xv2,gp[2]) + dot4(xv3,gp[3]);
    }
    #pragma unroll
    for (int e=0;e<NE;++e) {
      #pragma unroll
      for (int off=32; off; off>>=1) lg[e] += __shfl_xor(lg[e], off);
    }
    if (ln == 0) {
      float mx = lg[0];
      #pragma unroll
      for (int e=1;e<NE;++e) mx = fmaxf(mx, lg[e]);
      float p[NE], s = 0.f;
      #pragma unroll
      for (int e=0;e<NE;++e) { p[e] = __expf(lg[e]-mx); s += p[e]; }
      float inv = 1.f/s;
      #pragma unroll
      for (int e=0;e<NE;++e) p[e] *= inv;
      int e1 = 0;
      #pragma unroll
      for (int e=1;e<NE;++e) if (p[e] > p[e1]) e1 = e;     // first max (tie: lower idx)
      int e2 = (e1==0) ? 1 : 0;
      #pragma unroll
      for (int e=0;e<NE;++e) if (e!=e1 && p[e] > p[e2]) e2 = e;
      float ws2 = p[e1] + p[e2];
      tke[2*t]   = e1; tke[2*t+1] = e2;
      tkw[2*t]   = p[e1]/ws2; tkw[2*t+1] = p[e2]/ws2;
      atomicAdd(&s_cnt[e1], 1); atomicAdd(&s_cnt[e2], 1);
      #pragma unroll
      for (int e=0;e<NE;++e) atomicAdd(&s_ps[e], p[e]);
    }
  }
  __syncthreads();
  if (tid < NE) { atomicAdd(&meta->cnt[tid], s_cnt[tid]); atomicAdd(&meta->psum[tid], s_ps[tid]); }
}

__global__ void k_scan(Meta* __restrict__ meta, float* __restrict__ aux_out) {
  if (threadIdx.x == 0) {
    int s = 0;
    for (int e=0;e<NE;++e) { meta->seg[e] = s; s += ((meta->cnt[e]+BM-1)/BM)*BM; }
    meta->seg[NE] = s;
    float a = 0.f;
    for (int e=0;e<NE;++e)
      a += ((float)meta->cnt[e]/(float)TT) * (meta->psum[e]/(float)TT);
    aux_out[0] = (float)NE * 0.01f * a;
  }
}

__global__ void k_scatter(const int* __restrict__ tke,
                          Meta* __restrict__ meta, int* __restrict__ perm,
                          int* __restrict__ tslot) {
  int t = blockIdx.x*blockDim.x + threadIdx.x;
  if (t >= TT) return;
  for (int k=0;k<2;++k) {
    int e = tke[2*t+k];
    int pos = atomicAdd(&meta->cursor[e], 1);
    int slot = meta->seg[e] + pos;
    perm[slot]   = t;
    tslot[2*t+k] = slot;
  }
}

// ---- BK=64 staging with free XOR chunk-swizzle (round-4, conflict-free) ----
// ---- round-5: L2-locality block swizzle: XCD-chunked 1D grid + m-bands ----
// ---- round-7: cvt3 deleted; Wg/Wu cvt fused into router, Wd cvt into gemm1 ----

// fused gate+up+SwiGLU: act[slot, I] = silu(Xg) * Xu  (bf16)
// Blocks >= G1 instead convert Wd -> wdh (consumed by gemm2, the next kernel),
// filling this kernel's tail round with the otherwise-serial BW pass.
__launch_bounds__(256, 2)
__global__ void k_gemm1(const u16* __restrict__ xh, const u16* __restrict__ wgh, const u16* __restrict__ wuh,
                        const int* __restrict__ perm, const Meta* __restrict__ meta, u16* __restrict__ act,
                        const float* __restrict__ Wd, u16* __restrict__ wdh) {
  __shared__ u16 As[BM*BK], Gs[BM*BK], Us[BM*BK];
  int bid = blockIdx.x;
  if (bid >= G1) {
    const long per = (long)NE*ID*HD/8;
    long base = (long)(bid - G1)*256 + threadIdx.x;
    for (long idx = base; idx < per; idx += (long)G1_CVT*256)
      cvt8(Wd + idx*8, wdh + idx*8);
    return;
  }
  // bijective remap: bid -> (mt, nt). XCD chunk (2992=8*374), then bands of
  // 8 m-tiles * 22 n-tiles (=176; 17 bands). Band A (8*256KB=2MB) stays in
  // the XCD's 4MB L2 across all 22 n-sweeps.
  int wg  = (bid&7)*(G1/8) + (bid>>3);
  int band = wg/176, r = wg%176;
  int mt = band*8 + (r&7);
  int m0 = mt*BM;
  int n0 = (r>>3)*BM;
  int total = meta->seg[NE];
  if (m0 >= total) return;
  int e = 0;
  #pragma unroll
  for (int i=1;i<NE;++i) if (m0 >= meta->seg[i]) e = i;
  int tid = threadIdx.x;
  int srow = tid>>3;                       // 0..31
  int scol = ((tid&7) ^ (srow&7)) * 8;     // swizzled 16B chunk (u16 elems)
  const u16* zp = meta->zeros;
  int tok[4];
  const u16* ap[4]; const u16* gp[4]; const u16* up[4];
  #pragma unroll
  for (int j=0;j<4;++j) {
    tok[j] = perm[m0 + srow + 32*j];
    ap[j]  = xh + (size_t)(tok[j]<0?0:tok[j])*HD + scol;
    size_t rr = (size_t)e*ID + n0 + srow + 32*j;
    gp[j]  = wgh + rr*HD + scol;
    up[j]  = wuh + rr*HD + scol;
  }
  u16* lA = As + tid*8; u16* lG = Gs + tid*8; u16* lU = Us + tid*8;
  int wv = tid>>6, ln = tid&63;
  int wr = (wv>>1)*64, wc = (wv&1)*64;
  int lr = ln&15, kq = ln>>4;
  int kx = lr&7;                           // read-side chunk XOR
  f32x4 accg[4][4] = {};
  f32x4 accu[4][4] = {};
  for (int k0 = 0; k0 < HD; k0 += BK) {
    #pragma unroll
    for (int j=0;j<4;++j) {
      gll16(tok[j]<0 ? (const void*)zp : (const void*)(ap[j]+k0), lA + j*2048);
      gll16(gp[j]+k0, lG + j*2048);
      gll16(up[j]+k0, lU + j*2048);
    }
    __syncthreads();
    #pragma unroll
    for (int h=0; h<2; ++h) {
      int koff = ((h*4 + kq) ^ kx) * 8;
      bf16x8 af[4], gf[4], uf[4];
      #pragma unroll
      for (int m=0;m<4;++m) af[m] = *(const bf16x8*)&As[(wr+m*16+lr)*BK + koff];
      #pragma unroll
      for (int n=0;n<4;++n) {
        gf[n] = *(const bf16x8*)&Gs[(wc+n*16+lr)*BK + koff];
        uf[n] = *(const bf16x8*)&Us[(wc+n*16+lr)*BK + koff];
      }
      #pragma unroll
      for (int m=0;m<4;++m)
        #pragma unroll
        for (int n=0;n<4;++n) {
          accg[m][n] = __builtin_amdgcn_mfma_f32_16x16x32_bf16(af[m], gf[n], accg[m][n], 0,0,0);
          accu[m][n] = __builtin_amdgcn_mfma_f32_16x16x32_bf16(af[m], uf[n], accu[m][n], 0,0,0);
        }
    }
    __syncthreads();
  }
  int rb = wr + (ln>>4)*4;
  int cb = n0 + wc + (ln&15);
  #pragma unroll
  for (int m=0;m<4;++m)
    #pragma unroll
    for (int j=0;j<4;++j) {
      size_t row = (size_t)(m0 + rb + m*16 + j);
      u16* ap2 = act + row*ID + cb;
      #pragma unroll
      for (int n=0;n<4;++n) {
        float g = accg[m][n][j], u = accu[m][n][j];
        float sv = g / (1.f + __expf(-g));
        ap2[n*16] = f2bf(sv*u);
      }
    }
}

// down proj, single-N + K-split-2: y[kh][slot, n0..n0+127] partial over half of K.
// 64 acc AGPRs + ~104 VGPR -> 3 waves/SIMD -> 3 blocks/CU -> slots=768,
// grid 2176 -> 2.83 -> 3 rounds -> 94.4% utilization.
__launch_bounds__(256, 3)
__global__ void k_gemm2(const u16* __restrict__ act, const u16* __restrict__ wdh,
                        const Meta* __restrict__ meta, u16* __restrict__ y) {
  __shared__ u16 As[BM*BK], Bs[BM*BK];
  // bijective remap: XCD chunk (2176=8*272; XCDs 0-3 kh=0, 4-7 kh=1),
  // then bands of 8 m-tiles * 8 n-tiles (=64; 17 bands per kh-half).
  int bid = blockIdx.x;
  int wg  = (bid&7)*(G2/8) + (bid>>3);
  int kh  = (wg >= G2/2) ? 1 : 0;
  int w2  = wg - kh*(G2/2);
  int band = w2>>6, r = w2&63;
  int mt = band*8 + (r&7);
  int m0 = mt*BM;
  int n0 = (r>>3)*BM;
  int total = meta->seg[NE];
  if (m0 >= total) return;
  int e = 0;
  #pragma unroll
  for (int i=1;i<NE;++i) if (m0 >= meta->seg[i]) e = i;
  int kbase = kh * (ID/2);
  u16* yh = y + (size_t)kh*MAXSLOT*HD;
  int tid = threadIdx.x;
  int srow = tid>>3;
  int scol = ((tid&7) ^ (srow&7)) * 8;
  const u16* ab = act + (size_t)(m0 + srow)*ID + kbase + scol;
  const u16* b0 = wdh + ((size_t)e*HD + n0 + srow)*ID + kbase + scol;
  u16* lA = As + tid*8; u16* lB = Bs + tid*8;
  int wv = tid>>6, ln = tid&63;
  int wr = (wv>>1)*64, wc = (wv&1)*64;
  int lr = ln&15, kq = ln>>4;
  int kx = lr&7;
  f32x4 acc[4][4] = {};
  for (int k0 = 0; k0 < ID/2; k0 += BK) {
    #pragma unroll
    for (int j=0;j<4;++j) {
      gll16(ab + (size_t)j*32*ID + k0, lA + j*2048);
      gll16(b0 + (size_t)j*32*ID + k0, lB + j*2048);
    }
    __syncthreads();
    #pragma unroll
    for (int h=0; h<2; ++h) {
      int koff = ((h*4 + kq) ^ kx) * 8;
      bf16x8 af[4], bf[4];
      #pragma unroll
      for (int m=0;m<4;++m) af[m] = *(const bf16x8*)&As[(wr+m*16+lr)*BK + koff];
      #pragma unroll
      for (int n=0;n<4;++n) bf[n] = *(const bf16x8*)&Bs[(wc+n*16+lr)*BK + koff];
      #pragma unroll
      for (int m=0;m<4;++m)
        #pragma unroll
        for (int n=0;n<4;++n)
          acc[m][n] = __builtin_amdgcn_mfma_f32_16x16x32_bf16(af[m], bf[n], acc[m][n], 0,0,0);
    }
    __syncthreads();
  }
  int rb = wr + (ln>>4)*4;
  int cb = n0 + wc + (ln&15);
  #pragma unroll
  for (int m=0;m<4;++m)
    #pragma unroll
    for (int j=0;j<4;++j) {
      u16* yp = yh + (size_t)(m0 + rb + m*16 + j)*HD + cb;
      #pragma unroll
      for (int n=0;n<4;++n) yp[n*16] = f2bf(acc[m][n][j]);
    }
}

// out[t] = w0*(y0[s0]+y1[s0]) + w1*(y0[s1]+y1[s1])
__global__ void k_combine(const u16* __restrict__ y, const int* __restrict__ tslot,
                          const float* __restrict__ tkw, float* __restrict__ out) {
  int idx = blockIdx.x*blockDim.x + threadIdx.x;   // one per 8 elems of out
  int t = idx >> 7;                                // HD/8 = 128 chunks per row
  int c = (idx & 127) * 8;
  int s0 = tslot[2*t], s1 = tslot[2*t+1];
  float w0 = tkw[2*t], w1 = tkw[2*t+1];
  const size_t H2 = (size_t)MAXSLOT*HD;
  union { uint4 v; u16 h[8]; } a0, a1, b0, b1;
  a0.v = *(const uint4*)(y + (size_t)s0*HD + c);
  a1.v = *(const uint4*)(y + H2 + (size_t)s0*HD + c);
  b0.v = *(const uint4*)(y + (size_t)s1*HD + c);
  b1.v = *(const uint4*)(y + H2 + (size_t)s1*HD + c);
  float r[8];
  #pragma unroll
  for (int i=0;i<8;++i)
    r[i] = w0*(bf2f(a0.h[i]) + bf2f(a1.h[i])) + w1*(bf2f(b0.h[i]) + bf2f(b1.h[i]));
  float4 o0 = {r[0],r[1],r[2],r[3]}, o1 = {r[4],r[5],r[6],r[7]};
  float4* op = (float4*)(out + (size_t)t*HD + c);
  op[0] = o0; op[1] = o1;
}

extern "C" void kernel_launch(void* const* d_in, const int* in_sizes, int n_in,
                              void* d_out, int out_size, void* d_ws, size_t ws_size,
                              hipStream_t stream) {
  if (ws_size < WS_NEED) return;   // diagnostic: error would stay at poison signature
  const float* x  = (const float*)d_in[0];
  const float* gw = (const float*)d_in[1];
  const float* Wg = (const float*)d_in[2];
  const float* Wu = (const float*)d_in[3];
  const float* Wd = (const float*)d_in[4];
  float* out = (float*)d_out;
  char* ws = (char*)d_ws;
  u16* xh   = (u16*)(ws + OFF_XH);
  u16* wgh  = (u16*)(ws + OFF_WGH);
  u16* wdh  = (u16*)(ws + OFF_WDH);
  u16* act  = (u16*)(ws + OFF_ACT);
  int* perm = (int*)(ws + OFF_PERM);
  int* tke  = (int*)(ws + OFF_TID);
  int* tslot= (int*)(ws + OFF_TSLOT);
  float* tkw= (float*)(ws + OFF_TW);
  Meta* meta= (Meta*)(ws + OFF_META);
  u16* y    = (u16*)(ws + OFF_Y);
  u16* wuh  = (u16*)(ws + OFF_WUH);

  k_init   <<<128, 256, 0, stream>>>(perm, meta);
  k_router <<<RTR_BLK + RTR_CVT, 256, 0, stream>>>(x, gw, tke, tkw, xh, meta, Wg, Wu, wgh);
  k_scan   <<<1, 64, 0, stream>>>(meta, out + (size_t)TT*HD);
  k_scatter<<<32, 256, 0, stream>>>(tke, meta, perm, tslot);
  k_gemm1  <<<G1 + G1_CVT, 256, 0, stream>>>(xh, wgh, wuh, perm, meta, act, Wd, wdh);
  k_gemm2  <<<G2, 256, 0, stream>>>(act, wdh, meta, y);
  k_combine<<<TT*HD/8/256, 256, 0, stream>>>(y, tslot, tkw, out);
}

// Round 8
// 565.933 us; speedup vs baseline: 1.0051x; 1.0051x over previous
//
#include <hip/hip_runtime.h>

#define TT 8192      // tokens = B*S
#define HD 1024      // hidden
#define ID 2816      // intermediate
#define NE 8         // experts

typedef unsigned short u16;
typedef __attribute__((ext_vector_type(8))) __bf16 bf16x8;
typedef __attribute__((ext_vector_type(4))) float f32x4;

static constexpr int BM = 128;
static constexpr int BK = 64;
static constexpr int MAXSLOT = 17408;   // 136 tiles * 128 rows (16384 + worst-case pad)
static constexpr int MTILES  = 136;
static constexpr int NN1     = ID/BM;   // 22 n-tiles in gemm1
static constexpr int G1      = MTILES*NN1;   // 2992 GEMM work items; band 8m*22n=176, 17 bands
static constexpr int G1GRP   = 428;          // total groups of 8 in gemm1 grid (375 gemm + 53 cvt)
static constexpr int G1T     = G1GRP*8;      // 3424 blocks
static constexpr int CVT1N   = 53*8;         // 424 Wd-cvt blocks inside gemm1
static constexpr int G2      = MTILES*8*2;   // 2176; kh halves of 1088; band 8m*8n=64, 17 bands
static constexpr int INIT_BLK= 128;
static constexpr int INIT_CVT= 1024;         // Wg/Wu cvt blocks in k_init

struct Meta {
  u16   zeros[32];   // 64B zero page, 16B aligned (struct offset 0)
  int   cnt[NE];
  float psum[NE];
  int   cursor[NE];
  int   seg[12];     // seg[0..8] used (padded segment starts)
};

// workspace layout (all 16B-aligned)
static constexpr size_t OFF_XH    = 0;
static constexpr size_t OFF_WGH   = OFF_XH   + (size_t)TT*HD*2;
static constexpr size_t OFF_WUH   = OFF_WGH  + (size_t)NE*ID*HD*2;
static constexpr size_t OFF_WDH   = OFF_WUH  + (size_t)NE*ID*HD*2;
static constexpr size_t OFF_ACT   = OFF_WDH  + (size_t)NE*HD*ID*2;
static constexpr size_t OFF_PERM  = OFF_ACT  + (size_t)MAXSLOT*ID*2;
static constexpr size_t OFF_TID   = OFF_PERM + (size_t)MAXSLOT*4;
static constexpr size_t OFF_TSLOT = OFF_TID  + (size_t)TT*2*4;
static constexpr size_t OFF_TW    = OFF_TSLOT+ (size_t)TT*2*4;
static constexpr size_t OFF_META  = OFF_TW   + (size_t)TT*2*4;
static constexpr size_t WS_NEED   = OFF_META + sizeof(Meta);
// y: 2 bf16 K-half buffers [2][MAXSLOT][HD] (71.3 MB) overlay WGH+WUH (92.4 MB, dead after gemm1)
static constexpr size_t OFF_Y     = OFF_WGH;

__device__ __forceinline__ u16 f2bf(float f) {
  unsigned u = __float_as_uint(f);
  u += 0x7FFFu + ((u >> 16) & 1u);   // RNE
  return (u16)(u >> 16);
}
__device__ __forceinline__ float bf2f(u16 h) {
  return __uint_as_float(((unsigned)h) << 16);
}

__device__ __forceinline__ float dot4(float4 a, float4 b) {
  return a.x*b.x + a.y*b.y + a.z*b.z + a.w*b.w;
}

__device__ __forceinline__ void gll16(const void* g, void* l) {
  __builtin_amdgcn_global_load_lds(
      (const __attribute__((address_space(1))) void*)g,
      (__attribute__((address_space(3))) void*)l, 16, 0, 0);
}

__device__ __forceinline__ void cvt8(const float* __restrict__ src, u16* __restrict__ dst) {
  const float4* s4 = (const float4*)src;
  float4 a = s4[0], b = s4[1];
  union { u16 h[8]; uint4 v; } r;
  r.h[0]=f2bf(a.x); r.h[1]=f2bf(a.y); r.h[2]=f2bf(a.z); r.h[3]=f2bf(a.w);
  r.h[4]=f2bf(b.x); r.h[5]=f2bf(b.y); r.h[6]=f2bf(b.z); r.h[7]=f2bf(b.w);
  *(uint4*)dst = r.v;
}

// per-thread seg recompute from cnt (8-step scalar prefix; cnt final after router)
__device__ __forceinline__ void calc_seg(const Meta* meta, int* seg) {
  int s = 0;
  #pragma unroll
  for (int e=0;e<NE;++e) { seg[e] = s; s += ((meta->cnt[e]+BM-1)/BM)*BM; }
  seg[NE] = s;
}

// blocks < INIT_BLK: init perm/meta. blocks >= INIT_BLK: convert Wg|Wu -> wgh|wuh
// (disjoint data, no intra-kernel ordering needed).
__global__ void k_init(int* __restrict__ perm, Meta* __restrict__ meta,
                       const float* __restrict__ Wg, const float* __restrict__ Wu,
                       u16* __restrict__ wgh) {
  int bid = blockIdx.x, tid = threadIdx.x;
  if (bid >= INIT_BLK) {
    const long per = (long)NE*ID*HD/8;
    long base = (long)(bid - INIT_BLK)*256 + tid;
    for (long idx = base; idx < 2*per; idx += (long)INIT_CVT*256) {
      const float* src = (idx < per) ? (Wg + idx*8) : (Wu + (idx-per)*8);
      cvt8(src, wgh + idx*8);
    }
    return;
  }
  int gid  = bid*256 + tid;
  int nthr = INIT_BLK*256;
  for (int i = gid; i < MAXSLOT; i += nthr) perm[i] = -1;
  if (gid < 32) meta->zeros[gid] = 0;
  if (gid < NE) { meta->cnt[gid]=0; meta->psum[gid]=0.f; meta->cursor[gid]=0; }
}

// one wave per token; fp32 logits to match reference top-k selection.
// Also emits xh (bf16 copy of x) since every element passes through here anyway.
__global__ void k_router(const float* __restrict__ x, const float* __restrict__ gw,
                         int* __restrict__ tke, float* __restrict__ tkw,
                         u16* __restrict__ xh, Meta* __restrict__ meta) {
  __shared__ int   s_cnt[NE];
  __shared__ float s_ps[NE];
  int tid = threadIdx.x;
  if (tid < NE) { s_cnt[tid]=0; s_ps[tid]=0.f; }
  __syncthreads();
  int wv = tid>>6, ln = tid&63;
  for (int it = 0; it < 8; ++it) {
    int t = it*1024 + blockIdx.x*4 + wv;
    const float4* xp = (const float4*)(x + (size_t)t*HD + ln*16);
    float4 xv0=xp[0], xv1=xp[1], xv2=xp[2], xv3=xp[3];
    union { u16 h[8]; uint4 v; } r0, r1;
    r0.h[0]=f2bf(xv0.x); r0.h[1]=f2bf(xv0.y); r0.h[2]=f2bf(xv0.z); r0.h[3]=f2bf(xv0.w);
    r0.h[4]=f2bf(xv1.x); r0.h[5]=f2bf(xv1.y); r0.h[6]=f2bf(xv1.z); r0.h[7]=f2bf(xv1.w);
    r1.h[0]=f2bf(xv2.x); r1.h[1]=f2bf(xv2.y); r1.h[2]=f2bf(xv2.z); r1.h[3]=f2bf(xv2.w);
    r1.h[4]=f2bf(xv3.x); r1.h[5]=f2bf(xv3.y); r1.h[6]=f2bf(xv3.z); r1.h[7]=f2bf(xv3.w);
    uint4* xo = (uint4*)(xh + (size_t)t*HD + ln*16);
    xo[0] = r0.v; xo[1] = r1.v;
    float lg[NE];
    #pragma unroll
    for (int e=0;e<NE;++e) {
      const float4* gp = (const float4*)(gw + e*HD + ln*16);
      lg[e] = dot4(xv0,gp[0]) + dot4(xv1,gp[1]) + dot4(xv2,gp[2]) + dot4(xv3,gp[3]);
    }
    #pragma unroll
    for (int e=0;e<NE;++e) {
      #pragma unroll
      for (int off=32; off; off>>=1) lg[e] += __shfl_xor(lg[e], off);
    }
    if (ln == 0) {
      float mx = lg[0];
      #pragma unroll
      for (int e=1;e<NE;++e) mx = fmaxf(mx, lg[e]);
      float p[NE], s = 0.f;
      #pragma unroll
      for (int e=0;e<NE;++e) { p[e] = __expf(lg[e]-mx); s += p[e]; }
      float inv = 1.f/s;
      #pragma unroll
      for (int e=0;e<NE;++e) p[e] *= inv;
      int e1 = 0;
      #pragma unroll
      for (int e=1;e<NE;++e) if (p[e] > p[e1]) e1 = e;     // first max (tie: lower idx)
      int e2 = (e1==0) ? 1 : 0;
      #pragma unroll
      for (int e=0;e<NE;++e) if (e!=e1 && p[e] > p[e2]) e2 = e;
      float ws2 = p[e1] + p[e2];
      tke[2*t]   = e1; tke[2*t+1] = e2;
      tkw[2*t]   = p[e1]/ws2; tkw[2*t+1] = p[e2]/ws2;
      atomicAdd(&s_cnt[e1], 1); atomicAdd(&s_cnt[e2], 1);
      #pragma unroll
      for (int e=0;e<NE;++e) atomicAdd(&s_ps[e], p[e]);
    }
  }
  __syncthreads();
  if (tid < NE) { atomicAdd(&meta->cnt[tid], s_cnt[tid]); atomicAdd(&meta->psum[tid], s_ps[tid]); }
}

// scatter + (merged) scan: every thread recomputes seg locally; block 0 thread 0
// publishes meta->seg (read by the GEMMs, later kernels) and aux_loss.
__global__ void k_scatter(const int* __restrict__ tke,
                          Meta* __restrict__ meta, int* __restrict__ perm,
                          int* __restrict__ tslot, float* __restrict__ aux_out) {
  int seg[NE+1];
  calc_seg(meta, seg);
  if (blockIdx.x == 0 && threadIdx.x == 0) {
    #pragma unroll
    for (int e=0;e<=NE;++e) meta->seg[e] = seg[e];
    float a = 0.f;
    #pragma unroll
    for (int e=0;e<NE;++e)
      a += ((float)meta->cnt[e]/(float)TT) * (meta->psum[e]/(float)TT);
    aux_out[0] = (float)NE * 0.01f * a;
  }
  int t = blockIdx.x*blockDim.x + threadIdx.x;
  if (t >= TT) return;
  for (int k=0;k<2;++k) {
    int e = tke[2*t+k];
    int pos = atomicAdd(&meta->cursor[e], 1);
    int slot = seg[e] + pos;
    perm[slot]   = t;
    tslot[2*t+k] = slot;
  }
}

// ---- BK=64 staging with free XOR chunk-swizzle (round-4, conflict-free) ----
// ---- round-5: L2-locality block swizzle: XCD-chunked 1D grid + m-bands ----
// ---- round-8: Wd-cvt INTERLEAVED into gemm1 (1 group of 8 per 7 GEMM groups,
//      preserving bid%8 -> XCD lane balance); Wg/Wu cvt merged into k_init ----

// fused gate+up+SwiGLU: act[slot, I] = silu(Xg) * Xu  (bf16)
__launch_bounds__(256, 2)
__global__ void k_gemm1(const u16* __restrict__ xh, const u16* __restrict__ wgh, const u16* __restrict__ wuh,
                        const int* __restrict__ perm, const Meta* __restrict__ meta, u16* __restrict__ act,
                        const float* __restrict__ Wd, u16* __restrict__ wdh) {
  __shared__ u16 As[BM*BK], Gs[BM*BK], Us[BM*BK];
  int bid = blockIdx.x;
  int g = bid >> 3, l = bid & 7;           // group, XCD lane
  if ((g & 7) == 7) {
    // Wd-cvt block: streams a slice of Wd->wdh using gemm1's spare HBM BW.
    const long per = (long)NE*ID*HD/8;
    long base = (long)((g>>3)*8 + l)*256 + threadIdx.x;
    for (long idx = base; idx < per; idx += (long)CVT1N*256)
      cvt8(Wd + idx*8, wdh + idx*8);
    return;
  }
  int gg = g - ((g+1) >> 3);               // compacted gemm group index (0..374)
  int wg = l*375 + gg;                     // per-XCD contiguous chunk
  if (wg >= G1) return;                    // 8 spare slots on lane 7
  // band decomposition: 8 m-tiles * 22 n-tiles per band; band A (2MB) L2-resident
  int band = wg/176, r = wg%176;
  int mt = band*8 + (r&7);
  int m0 = mt*BM;
  int n0 = (r>>3)*BM;
  int total = meta->seg[NE];
  if (m0 >= total) return;
  int e = 0;
  #pragma unroll
  for (int i=1;i<NE;++i) if (m0 >= meta->seg[i]) e = i;
  int tid = threadIdx.x;
  int srow = tid>>3;                       // 0..31
  int scol = ((tid&7) ^ (srow&7)) * 8;     // swizzled 16B chunk (u16 elems)
  const u16* zp = meta->zeros;
  int tok[4];
  const u16* ap[4]; const u16* gp[4]; const u16* up[4];
  #pragma unroll
  for (int j=0;j<4;++j) {
    tok[j] = perm[m0 + srow + 32*j];
    ap[j]  = xh + (size_t)(tok[j]<0?0:tok[j])*HD + scol;
    size_t rr = (size_t)e*ID + n0 + srow + 32*j;
    gp[j]  = wgh + rr*HD + scol;
    up[j]  = wuh + rr*HD + scol;
  }
  u16* lA = As + tid*8; u16* lG = Gs + tid*8; u16* lU = Us + tid*8;
  int wv = tid>>6, ln = tid&63;
  int wr = (wv>>1)*64, wc = (wv&1)*64;
  int lr = ln&15, kq = ln>>4;
  int kx = lr&7;                           // read-side chunk XOR
  f32x4 accg[4][4] = {};
  f32x4 accu[4][4] = {};
  for (int k0 = 0; k0 < HD; k0 += BK) {
    #pragma unroll
    for (int j=0;j<4;++j) {
      gll16(tok[j]<0 ? (const void*)zp : (const void*)(ap[j]+k0), lA + j*2048);
      gll16(gp[j]+k0, lG + j*2048);
      gll16(up[j]+k0, lU + j*2048);
    }
    __syncthreads();
    #pragma unroll
    for (int h=0; h<2; ++h) {
      int koff = ((h*4 + kq) ^ kx) * 8;
      bf16x8 af[4], gf[4], uf[4];
      #pragma unroll
      for (int m=0;m<4;++m) af[m] = *(const bf16x8*)&As[(wr+m*16+lr)*BK + koff];
      #pragma unroll
      for (int n=0;n<4;++n) {
        gf[n] = *(const bf16x8*)&Gs[(wc+n*16+lr)*BK + koff];
        uf[n] = *(const bf16x8*)&Us[(wc+n*16+lr)*BK + koff];
      }
      #pragma unroll
      for (int m=0;m<4;++m)
        #pragma unroll
        for (int n=0;n<4;++n) {
          accg[m][n] = __builtin_amdgcn_mfma_f32_16x16x32_bf16(af[m], gf[n], accg[m][n], 0,0,0);
          accu[m][n] = __builtin_amdgcn_mfma_f32_16x16x32_bf16(af[m], uf[n], accu[m][n], 0,0,0);
        }
    }
    __syncthreads();
  }
  int rb = wr + (ln>>4)*4;
  int cb = n0 + wc + (ln&15);
  #pragma unroll
  for (int m=0;m<4;++m)
    #pragma unroll
    for (int j=0;j<4;++j) {
      size_t row = (size_t)(m0 + rb + m*16 + j);
      u16* ap2 = act + row*ID + cb;
      #pragma unroll
      for (int n=0;n<4;++n) {
        float g2 = accg[m][n][j], u = accu[m][n][j];
        float sv = g2 / (1.f + __expf(-g2));
        ap2[n*16] = f2bf(sv*u);
      }
    }
}

// down proj, single-N + K-split-2: y[kh][slot, n0..n0+127] partial over half of K.
// 64 acc AGPRs + ~104 VGPR -> 3 waves/SIMD -> 3 blocks/CU -> slots=768,
// grid 2176 -> 2.83 -> 3 rounds -> 94.4% utilization.
__launch_bounds__(256, 3)
__global__ void k_gemm2(const u16* __restrict__ act, const u16* __restrict__ wdh,
                        const Meta* __restrict__ meta, u16* __restrict__ y) {
  __shared__ u16 As[BM*BK], Bs[BM*BK];
  int bid = blockIdx.x;
  int wg  = (bid&7)*(G2/8) + (bid>>3);
  int kh  = (wg >= G2/2) ? 1 : 0;
  int w2  = wg - kh*(G2/2);
  int band = w2>>6, r = w2&63;
  int mt = band*8 + (r&7);
  int m0 = mt*BM;
  int n0 = (r>>3)*BM;
  int total = meta->seg[NE];
  if (m0 >= total) return;
  int e = 0;
  #pragma unroll
  for (int i=1;i<NE;++i) if (m0 >= meta->seg[i]) e = i;
  int kbase = kh * (ID/2);
  u16* yh = y + (size_t)kh*MAXSLOT*HD;
  int tid = threadIdx.x;
  int srow = tid>>3;
  int scol = ((tid&7) ^ (srow&7)) * 8;
  const u16* ab = act + (size_t)(m0 + srow)*ID + kbase + scol;
  const u16* b0 = wdh + ((size_t)e*HD + n0 + srow)*ID + kbase + scol;
  u16* lA = As + tid*8; u16* lB = Bs + tid*8;
  int wv = tid>>6, ln = tid&63;
  int wr = (wv>>1)*64, wc = (wv&1)*64;
  int lr = ln&15, kq = ln>>4;
  int kx = lr&7;
  f32x4 acc[4][4] = {};
  for (int k0 = 0; k0 < ID/2; k0 += BK) {
    #pragma unroll
    for (int j=0;j<4;++j) {
      gll16(ab + (size_t)j*32*ID + k0, lA + j*2048);
      gll16(b0 + (size_t)j*32*ID + k0, lB + j*2048);
    }
    __syncthreads();
    #pragma unroll
    for (int h=0; h<2; ++h) {
      int koff = ((h*4 + kq) ^ kx) * 8;
      bf16x8 af[4], bf[4];
      #pragma unroll
      for (int m=0;m<4;++m) af[m] = *(const bf16x8*)&As[(wr+m*16+lr)*BK + koff];
      #pragma unroll
      for (int n=0;n<4;++n) bf[n] = *(const bf16x8*)&Bs[(wc+n*16+lr)*BK + koff];
      #pragma unroll
      for (int m=0;m<4;++m)
        #pragma unroll
        for (int n=0;n<4;++n)
          acc[m][n] = __builtin_amdgcn_mfma_f32_16x16x32_bf16(af[m], bf[n], acc[m][n], 0,0,0);
    }
    __syncthreads();
  }
  int rb = wr + (ln>>4)*4;
  int cb = n0 + wc + (ln&15);
  #pragma unroll
  for (int m=0;m<4;++m)
    #pragma unroll
    for (int j=0;j<4;++j) {
      u16* yp = yh + (size_t)(m0 + rb + m*16 + j)*HD + cb;
      #pragma unroll
      for (int n=0;n<4;++n) yp[n*16] = f2bf(acc[m][n][j]);
    }
}

// out[t] = w0*(y0[s0]+y1[s0]) + w1*(y0[s1]+y1[s1])
__global__ void k_combine(const u16* __restrict__ y, const int* __restrict__ tslot,
                          const float* __restrict__ tkw, float* __restrict__ out) {
  int idx = blockIdx.x*blockDim.x + threadIdx.x;   // one per 8 elems of out
  int t = idx >> 7;                                // HD/8 = 128 chunks per row
  int c = (idx & 127) * 8;
  int s0 = tslot[2*t], s1 = tslot[2*t+1];
  float w0 = tkw[2*t], w1 = tkw[2*t+1];
  const size_t H2 = (size_t)MAXSLOT*HD;
  union { uint4 v; u16 h[8]; } a0, a1, b0, b1;
  a0.v = *(const uint4*)(y + (size_t)s0*HD + c);
  a1.v = *(const uint4*)(y + H2 + (size_t)s0*HD + c);
  b0.v = *(const uint4*)(y + (size_t)s1*HD + c);
  b1.v = *(const uint4*)(y + H2 + (size_t)s1*HD + c);
  float r[8];
  #pragma unroll
  for (int i=0;i<8;++i)
    r[i] = w0*(bf2f(a0.h[i]) + bf2f(a1.h[i])) + w1*(bf2f(b0.h[i]) + bf2f(b1.h[i]));
  float4 o0 = {r[0],r[1],r[2],r[3]}, o1 = {r[4],r[5],r[6],r[7]};
  float4* op = (float4*)(out + (size_t)t*HD + c);
  op[0] = o0; op[1] = o1;
}

extern "C" void kernel_launch(void* const* d_in, const int* in_sizes, int n_in,
                              void* d_out, int out_size, void* d_ws, size_t ws_size,
                              hipStream_t stream) {
  if (ws_size < WS_NEED) return;   // diagnostic: error would stay at poison signature
  const float* x  = (const float*)d_in[0];
  const float* gw = (const float*)d_in[1];
  const float* Wg = (const float*)d_in[2];
  const float* Wu = (const float*)d_in[3];
  const float* Wd = (const float*)d_in[4];
  float* out = (float*)d_out;
  char* ws = (char*)d_ws;
  u16* xh   = (u16*)(ws + OFF_XH);
  u16* wgh  = (u16*)(ws + OFF_WGH);
  u16* wuh  = (u16*)(ws + OFF_WUH);
  u16* wdh  = (u16*)(ws + OFF_WDH);
  u16* act  = (u16*)(ws + OFF_ACT);
  int* perm = (int*)(ws + OFF_PERM);
  int* tke  = (int*)(ws + OFF_TID);
  int* tslot= (int*)(ws + OFF_TSLOT);
  float* tkw= (float*)(ws + OFF_TW);
  Meta* meta= (Meta*)(ws + OFF_META);
  u16* y    = (u16*)(ws + OFF_Y);

  k_init   <<<INIT_BLK + INIT_CVT, 256, 0, stream>>>(perm, meta, Wg, Wu, wgh);
  k_router <<<256, 256, 0, stream>>>(x, gw, tke, tkw, xh, meta);
  k_scatter<<<32, 256, 0, stream>>>(tke, meta, perm, tslot, out + (size_t)TT*HD);
  k_gemm1  <<<G1T, 256, 0, stream>>>(xh, wgh, wuh, perm, meta, act, Wd, wdh);
  k_gemm2  <<<G2, 256, 0, stream>>>(act, wdh, meta, y);
  k_combine<<<TT*HD/8/256, 256, 0, stream>>>(y, tslot, tkw, out);
}

// Round 9
// 547.673 us; speedup vs baseline: 1.0386x; 1.0333x over previous
//
#include <hip/hip_runtime.h>

#define TT 8192      // tokens = B*S
#define HD 1024      // hidden
#define ID 2816      // intermediate
#define NE 8         // experts

typedef unsigned short u16;
typedef __attribute__((ext_vector_type(8))) __bf16 bf16x8;
typedef __attribute__((ext_vector_type(4))) float f32x4;

static constexpr int BM = 128;
static constexpr int BK = 64;
static constexpr int MAXSLOT = 17408;   // 136 tiles * 128 rows (16384 + worst-case pad)
static constexpr int MTILES  = 136;
static constexpr int NN1     = ID/BM;   // 22 n-tiles in gemm1
static constexpr int G1      = MTILES*NN1;   // 2992 = 8*374; band 8m*22n=176, 17 bands
static constexpr int G2      = MTILES*8*2;   // 2176; kh halves of 1088; band 8m*8n=64, 17 bands
static constexpr int INIT_BLK= 128;
static constexpr int INIT_CVT= 1024;         // Wg/Wu cvt blocks in k_init
static constexpr int CVTW_BLK= 1024;         // standalone Wd cvt blocks

struct Meta {
  u16   zeros[32];   // 64B zero page, 16B aligned (struct offset 0)
  int   cnt[NE];
  float psum[NE];
  int   cursor[NE];
  int   seg[12];     // seg[0..8] used (padded segment starts)
};

// workspace layout (all 16B-aligned)
static constexpr size_t OFF_XH    = 0;
static constexpr size_t OFF_WGH   = OFF_XH   + (size_t)TT*HD*2;
static constexpr size_t OFF_WUH   = OFF_WGH  + (size_t)NE*ID*HD*2;
static constexpr size_t OFF_WDH   = OFF_WUH  + (size_t)NE*ID*HD*2;
static constexpr size_t OFF_ACT   = OFF_WDH  + (size_t)NE*HD*ID*2;
static constexpr size_t OFF_PERM  = OFF_ACT  + (size_t)MAXSLOT*ID*2;
static constexpr size_t OFF_TID   = OFF_PERM + (size_t)MAXSLOT*4;
static constexpr size_t OFF_TSLOT = OFF_TID  + (size_t)TT*2*4;
static constexpr size_t OFF_TW    = OFF_TSLOT+ (size_t)TT*2*4;
static constexpr size_t OFF_META  = OFF_TW   + (size_t)TT*2*4;
static constexpr size_t WS_NEED   = OFF_META + sizeof(Meta);
// y: 2 bf16 K-half buffers [2][MAXSLOT][HD] (71.3 MB) overlay WGH+WUH (92.4 MB, dead after gemm1)
static constexpr size_t OFF_Y     = OFF_WGH;

__device__ __forceinline__ u16 f2bf(float f) {
  unsigned u = __float_as_uint(f);
  u += 0x7FFFu + ((u >> 16) & 1u);   // RNE
  return (u16)(u >> 16);
}
__device__ __forceinline__ float bf2f(u16 h) {
  return __uint_as_float(((unsigned)h) << 16);
}

__device__ __forceinline__ float dot4(float4 a, float4 b) {
  return a.x*b.x + a.y*b.y + a.z*b.z + a.w*b.w;
}

__device__ __forceinline__ void gll16(const void* g, void* l) {
  __builtin_amdgcn_global_load_lds(
      (const __attribute__((address_space(1))) void*)g,
      (__attribute__((address_space(3))) void*)l, 16, 0, 0);
}

__device__ __forceinline__ void cvt8(const float* __restrict__ src, u16* __restrict__ dst) {
  const float4* s4 = (const float4*)src;
  float4 a = s4[0], b = s4[1];
  union { u16 h[8]; uint4 v; } r;
  r.h[0]=f2bf(a.x); r.h[1]=f2bf(a.y); r.h[2]=f2bf(a.z); r.h[3]=f2bf(a.w);
  r.h[4]=f2bf(b.x); r.h[5]=f2bf(b.y); r.h[6]=f2bf(b.z); r.h[7]=f2bf(b.w);
  *(uint4*)dst = r.v;
}

// per-thread seg recompute from cnt (8-step scalar prefix; cnt final after router)
__device__ __forceinline__ void calc_seg(const Meta* meta, int* seg) {
  int s = 0;
  #pragma unroll
  for (int e=0;e<NE;++e) { seg[e] = s; s += ((meta->cnt[e]+BM-1)/BM)*BM; }
  seg[NE] = s;
}

// blocks < INIT_BLK: init perm/meta. blocks >= INIT_BLK: convert Wg|Wu -> wgh|wuh
// (disjoint data, no intra-kernel ordering needed).
__global__ void k_init(int* __restrict__ perm, Meta* __restrict__ meta,
                       const float* __restrict__ Wg, const float* __restrict__ Wu,
                       u16* __restrict__ wgh) {
  int bid = blockIdx.x, tid = threadIdx.x;
  if (bid >= INIT_BLK) {
    const long per = (long)NE*ID*HD/8;
    long base = (long)(bid - INIT_BLK)*256 + tid;
    for (long idx = base; idx < 2*per; idx += (long)INIT_CVT*256) {
      const float* src = (idx < per) ? (Wg + idx*8) : (Wu + (idx-per)*8);
      cvt8(src, wgh + idx*8);
    }
    return;
  }
  int gid  = bid*256 + tid;
  int nthr = INIT_BLK*256;
  for (int i = gid; i < MAXSLOT; i += nthr) perm[i] = -1;
  if (gid < 32) meta->zeros[gid] = 0;
  if (gid < NE) { meta->cnt[gid]=0; meta->psum[gid]=0.f; meta->cursor[gid]=0; }
}

// standalone Wd -> wdh cvt (consumed by gemm2). Co-residency with gemm1 was
// measured harmful twice (r7 append, r8 interleave: slot theft + L2-band
// eviction) -- keep it a clean serial BW pass (~24us).
__global__ void k_cvtw(const float* __restrict__ Wd, u16* __restrict__ wdh) {
  const long per = (long)NE*ID*HD/8;
  for (long idx = (long)blockIdx.x*blockDim.x + threadIdx.x; idx < per;
       idx += (long)CVTW_BLK*256)
    cvt8(Wd + idx*8, wdh + idx*8);
}

// one wave per token; fp32 logits to match reference top-k selection.
// Also emits xh (bf16 copy of x) since every element passes through here anyway.
// 512 blocks -> 2 blocks/CU resident (8 waves) to hide the serial lane-0 tail.
__global__ void k_router(const float* __restrict__ x, const float* __restrict__ gw,
                         int* __restrict__ tke, float* __restrict__ tkw,
                         u16* __restrict__ xh, Meta* __restrict__ meta) {
  __shared__ int   s_cnt[NE];
  __shared__ float s_ps[NE];
  int tid = threadIdx.x;
  if (tid < NE) { s_cnt[tid]=0; s_ps[tid]=0.f; }
  __syncthreads();
  int wv = tid>>6, ln = tid&63;
  for (int it = 0; it < 4; ++it) {
    int t = it*2048 + blockIdx.x*4 + wv;
    const float4* xp = (const float4*)(x + (size_t)t*HD + ln*16);
    float4 xv0=xp[0], xv1=xp[1], xv2=xp[2], xv3=xp[3];
    union { u16 h[8]; uint4 v; } r0, r1;
    r0.h[0]=f2bf(xv0.x); r0.h[1]=f2bf(xv0.y); r0.h[2]=f2bf(xv0.z); r0.h[3]=f2bf(xv0.w);
    r0.h[4]=f2bf(xv1.x); r0.h[5]=f2bf(xv1.y); r0.h[6]=f2bf(xv1.z); r0.h[7]=f2bf(xv1.w);
    r1.h[0]=f2bf(xv2.x); r1.h[1]=f2bf(xv2.y); r1.h[2]=f2bf(xv2.z); r1.h[3]=f2bf(xv2.w);
    r1.h[4]=f2bf(xv3.x); r1.h[5]=f2bf(xv3.y); r1.h[6]=f2bf(xv3.z); r1.h[7]=f2bf(xv3.w);
    uint4* xo = (uint4*)(xh + (size_t)t*HD + ln*16);
    xo[0] = r0.v; xo[1] = r1.v;
    float lg[NE];
    #pragma unroll
    for (int e=0;e<NE;++e) {
      const float4* gp = (const float4*)(gw + e*HD + ln*16);
      lg[e] = dot4(xv0,gp[0]) + dot4(xv1,gp[1]) + dot4(xv2,gp[2]) + dot4(xv3,gp[3]);
    }
    #pragma unroll
    for (int e=0;e<NE;++e) {
      #pragma unroll
      for (int off=32; off; off>>=1) lg[e] += __shfl_xor(lg[e], off);
    }
    if (ln == 0) {
      float mx = lg[0];
      #pragma unroll
      for (int e=1;e<NE;++e) mx = fmaxf(mx, lg[e]);
      float p[NE], s = 0.f;
      #pragma unroll
      for (int e=0;e<NE;++e) { p[e] = __expf(lg[e]-mx); s += p[e]; }
      float inv = 1.f/s;
      #pragma unroll
      for (int e=0;e<NE;++e) p[e] *= inv;
      int e1 = 0;
      #pragma unroll
      for (int e=1;e<NE;++e) if (p[e] > p[e1]) e1 = e;     // first max (tie: lower idx)
      int e2 = (e1==0) ? 1 : 0;
      #pragma unroll
      for (int e=0;e<NE;++e) if (e!=e1 && p[e] > p[e2]) e2 = e;
      float ws2 = p[e1] + p[e2];
      tke[2*t]   = e1; tke[2*t+1] = e2;
      tkw[2*t]   = p[e1]/ws2; tkw[2*t+1] = p[e2]/ws2;
      atomicAdd(&s_cnt[e1], 1); atomicAdd(&s_cnt[e2], 1);
      #pragma unroll
      for (int e=0;e<NE;++e) atomicAdd(&s_ps[e], p[e]);
    }
  }
  __syncthreads();
  if (tid < NE) { atomicAdd(&meta->cnt[tid], s_cnt[tid]); atomicAdd(&meta->psum[tid], s_ps[tid]); }
}

// scatter + (merged) scan: every thread recomputes seg locally; block 0 thread 0
// publishes meta->seg (read by the GEMMs, later kernels) and aux_loss.
__global__ void k_scatter(const int* __restrict__ tke,
                          Meta* __restrict__ meta, int* __restrict__ perm,
                          int* __restrict__ tslot, float* __restrict__ aux_out) {
  int seg[NE+1];
  calc_seg(meta, seg);
  if (blockIdx.x == 0 && threadIdx.x == 0) {
    #pragma unroll
    for (int e=0;e<=NE;++e) meta->seg[e] = seg[e];
    float a = 0.f;
    #pragma unroll
    for (int e=0;e<NE;++e)
      a += ((float)meta->cnt[e]/(float)TT) * (meta->psum[e]/(float)TT);
    aux_out[0] = (float)NE * 0.01f * a;
  }
  int t = blockIdx.x*blockDim.x + threadIdx.x;
  if (t >= TT) return;
  for (int k=0;k<2;++k) {
    int e = tke[2*t+k];
    int pos = atomicAdd(&meta->cursor[e], 1);
    int slot = seg[e] + pos;
    perm[slot]   = t;
    tslot[2*t+k] = slot;
  }
}

// ---- BK=64 staging with free XOR chunk-swizzle (round-4, conflict-free) ----
// ---- round-5: L2-locality block swizzle: XCD-chunked 1D grid + m-bands ----
// ---- round-9: gemm1 restored to pure round-6 form (221us / MfmaUtil 39) ----

// fused gate+up+SwiGLU: act[slot, I] = silu(Xg) * Xu  (bf16)
__launch_bounds__(256, 2)
__global__ void k_gemm1(const u16* __restrict__ xh, const u16* __restrict__ wgh, const u16* __restrict__ wuh,
                        const int* __restrict__ perm, const Meta* __restrict__ meta, u16* __restrict__ act) {
  __shared__ u16 As[BM*BK], Gs[BM*BK], Us[BM*BK];
  // bijective remap: bid -> (mt, nt). XCD chunk (2992=8*374), then bands of
  // 8 m-tiles * 22 n-tiles (=176; 17 bands). Band A (2MB) stays in the
  // XCD's 4MB L2 across all 22 n-sweeps.
  int bid = blockIdx.x;
  int wg  = (bid&7)*(G1/8) + (bid>>3);
  int band = wg/176, r = wg%176;
  int mt = band*8 + (r&7);
  int m0 = mt*BM;
  int n0 = (r>>3)*BM;
  int total = meta->seg[NE];
  if (m0 >= total) return;
  int e = 0;
  #pragma unroll
  for (int i=1;i<NE;++i) if (m0 >= meta->seg[i]) e = i;
  int tid = threadIdx.x;
  int srow = tid>>3;                       // 0..31
  int scol = ((tid&7) ^ (srow&7)) * 8;     // swizzled 16B chunk (u16 elems)
  const u16* zp = meta->zeros;
  int tok[4];
  const u16* ap[4]; const u16* gp[4]; const u16* up[4];
  #pragma unroll
  for (int j=0;j<4;++j) {
    tok[j] = perm[m0 + srow + 32*j];
    ap[j]  = xh + (size_t)(tok[j]<0?0:tok[j])*HD + scol;
    size_t rr = (size_t)e*ID + n0 + srow + 32*j;
    gp[j]  = wgh + rr*HD + scol;
    up[j]  = wuh + rr*HD + scol;
  }
  u16* lA = As + tid*8; u16* lG = Gs + tid*8; u16* lU = Us + tid*8;
  int wv = tid>>6, ln = tid&63;
  int wr = (wv>>1)*64, wc = (wv&1)*64;
  int lr = ln&15, kq = ln>>4;
  int kx = lr&7;                           // read-side chunk XOR
  f32x4 accg[4][4] = {};
  f32x4 accu[4][4] = {};
  for (int k0 = 0; k0 < HD; k0 += BK) {
    #pragma unroll
    for (int j=0;j<4;++j) {
      gll16(tok[j]<0 ? (const void*)zp : (const void*)(ap[j]+k0), lA + j*2048);
      gll16(gp[j]+k0, lG + j*2048);
      gll16(up[j]+k0, lU + j*2048);
    }
    __syncthreads();
    #pragma unroll
    for (int h=0; h<2; ++h) {
      int koff = ((h*4 + kq) ^ kx) * 8;
      bf16x8 af[4], gf[4], uf[4];
      #pragma unroll
      for (int m=0;m<4;++m) af[m] = *(const bf16x8*)&As[(wr+m*16+lr)*BK + koff];
      #pragma unroll
      for (int n=0;n<4;++n) {
        gf[n] = *(const bf16x8*)&Gs[(wc+n*16+lr)*BK + koff];
        uf[n] = *(const bf16x8*)&Us[(wc+n*16+lr)*BK + koff];
      }
      #pragma unroll
      for (int m=0;m<4;++m)
        #pragma unroll
        for (int n=0;n<4;++n) {
          accg[m][n] = __builtin_amdgcn_mfma_f32_16x16x32_bf16(af[m], gf[n], accg[m][n], 0,0,0);
          accu[m][n] = __builtin_amdgcn_mfma_f32_16x16x32_bf16(af[m], uf[n], accu[m][n], 0,0,0);
        }
    }
    __syncthreads();
  }
  int rb = wr + (ln>>4)*4;
  int cb = n0 + wc + (ln&15);
  #pragma unroll
  for (int m=0;m<4;++m)
    #pragma unroll
    for (int j=0;j<4;++j) {
      size_t row = (size_t)(m0 + rb + m*16 + j);
      u16* ap2 = act + row*ID + cb;
      #pragma unroll
      for (int n=0;n<4;++n) {
        float g2 = accg[m][n][j], u = accu[m][n][j];
        float sv = g2 / (1.f + __expf(-g2));
        ap2[n*16] = f2bf(sv*u);
      }
    }
}

// down proj, single-N + K-split-2: y[kh][slot, n0..n0+127] partial over half of K.
// 64 acc AGPRs + ~104 VGPR -> 3 waves/SIMD -> 3 blocks/CU -> slots=768,
// grid 2176 -> 2.83 -> 3 rounds -> 94.4% utilization.
__launch_bounds__(256, 3)
__global__ void k_gemm2(const u16* __restrict__ act, const u16* __restrict__ wdh,
                        const Meta* __restrict__ meta, u16* __restrict__ y) {
  __shared__ u16 As[BM*BK], Bs[BM*BK];
  int bid = blockIdx.x;
  int wg  = (bid&7)*(G2/8) + (bid>>3);
  int kh  = (wg >= G2/2) ? 1 : 0;
  int w2  = wg - kh*(G2/2);
  int band = w2>>6, r = w2&63;
  int mt = band*8 + (r&7);
  int m0 = mt*BM;
  int n0 = (r>>3)*BM;
  int total = meta->seg[NE];
  if (m0 >= total) return;
  int e = 0;
  #pragma unroll
  for (int i=1;i<NE;++i) if (m0 >= meta->seg[i]) e = i;
  int kbase = kh * (ID/2);
  u16* yh = y + (size_t)kh*MAXSLOT*HD;
  int tid = threadIdx.x;
  int srow = tid>>3;
  int scol = ((tid&7) ^ (srow&7)) * 8;
  const u16* ab = act + (size_t)(m0 + srow)*ID + kbase + scol;
  const u16* b0 = wdh + ((size_t)e*HD + n0 + srow)*ID + kbase + scol;
  u16* lA = As + tid*8; u16* lB = Bs + tid*8;
  int wv = tid>>6, ln = tid&63;
  int wr = (wv>>1)*64, wc = (wv&1)*64;
  int lr = ln&15, kq = ln>>4;
  int kx = lr&7;
  f32x4 acc[4][4] = {};
  for (int k0 = 0; k0 < ID/2; k0 += BK) {
    #pragma unroll
    for (int j=0;j<4;++j) {
      gll16(ab + (size_t)j*32*ID + k0, lA + j*2048);
      gll16(b0 + (size_t)j*32*ID + k0, lB + j*2048);
    }
    __syncthreads();
    #pragma unroll
    for (int h=0; h<2; ++h) {
      int koff = ((h*4 + kq) ^ kx) * 8;
      bf16x8 af[4], bf[4];
      #pragma unroll
      for (int m=0;m<4;++m) af[m] = *(const bf16x8*)&As[(wr+m*16+lr)*BK + koff];
      #pragma unroll
      for (int n=0;n<4;++n) bf[n] = *(const bf16x8*)&Bs[(wc+n*16+lr)*BK + koff];
      #pragma unroll
      for (int m=0;m<4;++m)
        #pragma unroll
        for (int n=0;n<4;++n)
          acc[m][n] = __builtin_amdgcn_mfma_f32_16x16x32_bf16(af[m], bf[n], acc[m][n], 0,0,0);
    }
    __syncthreads();
  }
  int rb = wr + (ln>>4)*4;
  int cb = n0 + wc + (ln&15);
  #pragma unroll
  for (int m=0;m<4;++m)
    #pragma unroll
    for (int j=0;j<4;++j) {
      u16* yp = yh + (size_t)(m0 + rb + m*16 + j)*HD + cb;
      #pragma unroll
      for (int n=0;n<4;++n) yp[n*16] = f2bf(acc[m][n][j]);
    }
}

// out[t] = w0*(y0[s0]+y1[s0]) + w1*(y0[s1]+y1[s1])
__global__ void k_combine(const u16* __restrict__ y, const int* __restrict__ tslot,
                          const float* __restrict__ tkw, float* __restrict__ out) {
  int idx = blockIdx.x*blockDim.x + threadIdx.x;   // one per 8 elems of out
  int t = idx >> 7;                                // HD/8 = 128 chunks per row
  int c = (idx & 127) * 8;
  int s0 = tslot[2*t], s1 = tslot[2*t+1];
  float w0 = tkw[2*t], w1 = tkw[2*t+1];
  const size_t H2 = (size_t)MAXSLOT*HD;
  union { uint4 v; u16 h[8]; } a0, a1, b0, b1;
  a0.v = *(const uint4*)(y + (size_t)s0*HD + c);
  a1.v = *(const uint4*)(y + H2 + (size_t)s0*HD + c);
  b0.v = *(const uint4*)(y + (size_t)s1*HD + c);
  b1.v = *(const uint4*)(y + H2 + (size_t)s1*HD + c);
  float r[8];
  #pragma unroll
  for (int i=0;i<8;++i)
    r[i] = w0*(bf2f(a0.h[i]) + bf2f(a1.h[i])) + w1*(bf2f(b0.h[i]) + bf2f(b1.h[i]));
  float4 o0 = {r[0],r[1],r[2],r[3]}, o1 = {r[4],r[5],r[6],r[7]};
  float4* op = (float4*)(out + (size_t)t*HD + c);
  op[0] = o0; op[1] = o1;
}

extern "C" void kernel_launch(void* const* d_in, const int* in_sizes, int n_in,
                              void* d_out, int out_size, void* d_ws, size_t ws_size,
                              hipStream_t stream) {
  if (ws_size < WS_NEED) return;   // diagnostic: error would stay at poison signature
  const float* x  = (const float*)d_in[0];
  const float* gw = (const float*)d_in[1];
  const float* Wg = (const float*)d_in[2];
  const float* Wu = (const float*)d_in[3];
  const float* Wd = (const float*)d_in[4];
  float* out = (float*)d_out;
  char* ws = (char*)d_ws;
  u16* xh   = (u16*)(ws + OFF_XH);
  u16* wgh  = (u16*)(ws + OFF_WGH);
  u16* wuh  = (u16*)(ws + OFF_WUH);
  u16* wdh  = (u16*)(ws + OFF_WDH);
  u16* act  = (u16*)(ws + OFF_ACT);
  int* perm = (int*)(ws + OFF_PERM);
  int* tke  = (int*)(ws + OFF_TID);
  int* tslot= (int*)(ws + OFF_TSLOT);
  float* tkw= (float*)(ws + OFF_TW);
  Meta* meta= (Meta*)(ws + OFF_META);
  u16* y    = (u16*)(ws + OFF_Y);

  k_init   <<<INIT_BLK + INIT_CVT, 256, 0, stream>>>(perm, meta, Wg, Wu, wgh);
  k_router <<<512, 256, 0, stream>>>(x, gw, tke, tkw, xh, meta);
  k_scatter<<<32, 256, 0, stream>>>(tke, meta, perm, tslot, out + (size_t)TT*HD);
  k_cvtw   <<<CVTW_BLK, 256, 0, stream>>>(Wd, wdh);
  k_gemm1  <<<G1, 256, 0, stream>>>(xh, wgh, wuh, perm, meta, act);
  k_gemm2  <<<G2, 256, 0, stream>>>(act, wdh, meta, y);
  k_combine<<<TT*HD/8/256, 256, 0, stream>>>(y, tslot, tkw, out);
}

// Round 10
// 535.458 us; speedup vs baseline: 1.0623x; 1.0228x over previous
//
#include <hip/hip_runtime.h>

#define TT 8192      // tokens = B*S
#define HD 1024      // hidden
#define ID 2816      // intermediate
#define NE 8         // experts

typedef unsigned short u16;
typedef __attribute__((ext_vector_type(8))) __bf16 bf16x8;
typedef __attribute__((ext_vector_type(4))) float f32x4;

static constexpr int BM = 128;
static constexpr int BK = 64;
static constexpr int MAXSLOT = 17408;   // 136 tiles * 128 rows (16384 + worst-case pad)
static constexpr int MTILES  = 136;
static constexpr int NN1     = ID/BM;   // 22 n-tiles in gemm1
static constexpr int G1      = MTILES*NN1;   // 2992 = 8*374; band 8m*22n=176, 17 bands
static constexpr int G2      = MTILES*8*2;   // 2176; kh halves of 1088; band 8m*8n=64, 17 bands
static constexpr int INIT_BLK= 128;
static constexpr int INIT_CVT= 1024;         // Wg/Wu cvt blocks in k_init
static constexpr int SCAT_BLK= 32;           // scatter compute blocks
static constexpr int SCAT_CVT= 1024;         // Wd cvt blocks fused into scatter

struct Meta {
  u16   zeros[32];   // 64B zero page, 16B aligned (struct offset 0)
  int   cnt[NE];
  float psum[NE];
  int   cursor[NE];
  int   seg[12];     // seg[0..8] used (padded segment starts)
};

// workspace layout (all 16B-aligned)
static constexpr size_t OFF_XH    = 0;
static constexpr size_t OFF_WGH   = OFF_XH   + (size_t)TT*HD*2;
static constexpr size_t OFF_WUH   = OFF_WGH  + (size_t)NE*ID*HD*2;
static constexpr size_t OFF_WDH   = OFF_WUH  + (size_t)NE*ID*HD*2;
static constexpr size_t OFF_ACT   = OFF_WDH  + (size_t)NE*HD*ID*2;
static constexpr size_t OFF_PERM  = OFF_ACT  + (size_t)MAXSLOT*ID*2;
static constexpr size_t OFF_TID   = OFF_PERM + (size_t)MAXSLOT*4;
static constexpr size_t OFF_TSLOT = OFF_TID  + (size_t)TT*2*4;
static constexpr size_t OFF_TW    = OFF_TSLOT+ (size_t)TT*2*4;
static constexpr size_t OFF_META  = OFF_TW   + (size_t)TT*2*4;
static constexpr size_t WS_NEED   = OFF_META + sizeof(Meta);
// y: 2 bf16 K-half buffers [2][MAXSLOT][HD] (71.3 MB) overlay WGH+WUH (92.4 MB, dead after gemm1)
static constexpr size_t OFF_Y     = OFF_WGH;

__device__ __forceinline__ u16 f2bf(float f) {
  unsigned u = __float_as_uint(f);
  u += 0x7FFFu + ((u >> 16) & 1u);   // RNE
  return (u16)(u >> 16);
}
__device__ __forceinline__ float bf2f(u16 h) {
  return __uint_as_float(((unsigned)h) << 16);
}

__device__ __forceinline__ float dot4(float4 a, float4 b) {
  return a.x*b.x + a.y*b.y + a.z*b.z + a.w*b.w;
}

__device__ __forceinline__ void gll16(const void* g, void* l) {
  __builtin_amdgcn_global_load_lds(
      (const __attribute__((address_space(1))) void*)g,
      (__attribute__((address_space(3))) void*)l, 16, 0, 0);
}

__device__ __forceinline__ void cvt8(const float* __restrict__ src, u16* __restrict__ dst) {
  const float4* s4 = (const float4*)src;
  float4 a = s4[0], b = s4[1];
  union { u16 h[8]; uint4 v; } r;
  r.h[0]=f2bf(a.x); r.h[1]=f2bf(a.y); r.h[2]=f2bf(a.z); r.h[3]=f2bf(a.w);
  r.h[4]=f2bf(b.x); r.h[5]=f2bf(b.y); r.h[6]=f2bf(b.z); r.h[7]=f2bf(b.w);
  *(uint4*)dst = r.v;
}

// per-thread seg recompute from cnt (8-step scalar prefix; cnt final after router)
__device__ __forceinline__ void calc_seg(const Meta* meta, int* seg) {
  int s = 0;
  #pragma unroll
  for (int e=0;e<NE;++e) { seg[e] = s; s += ((meta->cnt[e]+BM-1)/BM)*BM; }
  seg[NE] = s;
}

// blocks < INIT_BLK: init perm/meta. blocks >= INIT_BLK: convert Wg|Wu -> wgh|wuh
// (disjoint data, no intra-kernel ordering needed).
__global__ void k_init(int* __restrict__ perm, Meta* __restrict__ meta,
                       const float* __restrict__ Wg, const float* __restrict__ Wu,
                       u16* __restrict__ wgh) {
  int bid = blockIdx.x, tid = threadIdx.x;
  if (bid >= INIT_BLK) {
    const long per = (long)NE*ID*HD/8;
    long base = (long)(bid - INIT_BLK)*256 + tid;
    for (long idx = base; idx < 2*per; idx += (long)INIT_CVT*256) {
      const float* src = (idx < per) ? (Wg + idx*8) : (Wu + (idx-per)*8);
      cvt8(src, wgh + idx*8);
    }
    return;
  }
  int gid  = bid*256 + tid;
  int nthr = INIT_BLK*256;
  for (int i = gid; i < MAXSLOT; i += nthr) perm[i] = -1;
  if (gid < 32) meta->zeros[gid] = 0;
  if (gid < NE) { meta->cnt[gid]=0; meta->psum[gid]=0.f; meta->cursor[gid]=0; }
}

// one wave per token; fp32 logits to match reference top-k selection.
// Also emits xh (bf16 copy of x) since every element passes through here anyway.
// 512 blocks -> 2 blocks/CU resident (8 waves) to hide the serial lane-0 tail.
__global__ void k_router(const float* __restrict__ x, const float* __restrict__ gw,
                         int* __restrict__ tke, float* __restrict__ tkw,
                         u16* __restrict__ xh, Meta* __restrict__ meta) {
  __shared__ int   s_cnt[NE];
  __shared__ float s_ps[NE];
  int tid = threadIdx.x;
  if (tid < NE) { s_cnt[tid]=0; s_ps[tid]=0.f; }
  __syncthreads();
  int wv = tid>>6, ln = tid&63;
  for (int it = 0; it < 4; ++it) {
    int t = it*2048 + blockIdx.x*4 + wv;
    const float4* xp = (const float4*)(x + (size_t)t*HD + ln*16);
    float4 xv0=xp[0], xv1=xp[1], xv2=xp[2], xv3=xp[3];
    union { u16 h[8]; uint4 v; } r0, r1;
    r0.h[0]=f2bf(xv0.x); r0.h[1]=f2bf(xv0.y); r0.h[2]=f2bf(xv0.z); r0.h[3]=f2bf(xv0.w);
    r0.h[4]=f2bf(xv1.x); r0.h[5]=f2bf(xv1.y); r0.h[6]=f2bf(xv1.z); r0.h[7]=f2bf(xv1.w);
    r1.h[0]=f2bf(xv2.x); r1.h[1]=f2bf(xv2.y); r1.h[2]=f2bf(xv2.z); r1.h[3]=f2bf(xv2.w);
    r1.h[4]=f2bf(xv3.x); r1.h[5]=f2bf(xv3.y); r1.h[6]=f2bf(xv3.z); r1.h[7]=f2bf(xv3.w);
    uint4* xo = (uint4*)(xh + (size_t)t*HD + ln*16);
    xo[0] = r0.v; xo[1] = r1.v;
    float lg[NE];
    #pragma unroll
    for (int e=0;e<NE;++e) {
      const float4* gp = (const float4*)(gw + e*HD + ln*16);
      lg[e] = dot4(xv0,gp[0]) + dot4(xv1,gp[1]) + dot4(xv2,gp[2]) + dot4(xv3,gp[3]);
    }
    #pragma unroll
    for (int e=0;e<NE;++e) {
      #pragma unroll
      for (int off=32; off; off>>=1) lg[e] += __shfl_xor(lg[e], off);
    }
    if (ln == 0) {
      float mx = lg[0];
      #pragma unroll
      for (int e=1;e<NE;++e) mx = fmaxf(mx, lg[e]);
      float p[NE], s = 0.f;
      #pragma unroll
      for (int e=0;e<NE;++e) { p[e] = __expf(lg[e]-mx); s += p[e]; }
      float inv = 1.f/s;
      #pragma unroll
      for (int e=0;e<NE;++e) p[e] *= inv;
      int e1 = 0;
      #pragma unroll
      for (int e=1;e<NE;++e) if (p[e] > p[e1]) e1 = e;     // first max (tie: lower idx)
      int e2 = (e1==0) ? 1 : 0;
      #pragma unroll
      for (int e=0;e<NE;++e) if (e!=e1 && p[e] > p[e2]) e2 = e;
      float ws2 = p[e1] + p[e2];
      tke[2*t]   = e1; tke[2*t+1] = e2;
      tkw[2*t]   = p[e1]/ws2; tkw[2*t+1] = p[e2]/ws2;
      atomicAdd(&s_cnt[e1], 1); atomicAdd(&s_cnt[e2], 1);
      #pragma unroll
      for (int e=0;e<NE;++e) atomicAdd(&s_ps[e], p[e]);
    }
  }
  __syncthreads();
  if (tid < NE) { atomicAdd(&meta->cnt[tid], s_cnt[tid]); atomicAdd(&meta->psum[tid], s_ps[tid]); }
}

// blocks < SCAT_BLK: scatter (+merged scan: every thread recomputes seg locally;
// block 0 thread 0 publishes meta->seg and aux_loss).
// blocks >= SCAT_BLK: standalone Wd->wdh cvt (consumed by gemm2; disjoint data).
// Co-residency of cvt with the GEMMs was measured harmful twice (r7/r8: slot
// theft + L2-band eviction); co-residency with tiny scatter is free.
__global__ void k_scatter(const int* __restrict__ tke,
                          Meta* __restrict__ meta, int* __restrict__ perm,
                          int* __restrict__ tslot, float* __restrict__ aux_out,
                          const float* __restrict__ Wd, u16* __restrict__ wdh) {
  if (blockIdx.x >= SCAT_BLK) {
    const long per = (long)NE*ID*HD/8;
    long base = (long)(blockIdx.x - SCAT_BLK)*256 + threadIdx.x;
    for (long idx = base; idx < per; idx += (long)SCAT_CVT*256)
      cvt8(Wd + idx*8, wdh + idx*8);
    return;
  }
  int seg[NE+1];
  calc_seg(meta, seg);
  if (blockIdx.x == 0 && threadIdx.x == 0) {
    #pragma unroll
    for (int e=0;e<=NE;++e) meta->seg[e] = seg[e];
    float a = 0.f;
    #pragma unroll
    for (int e=0;e<NE;++e)
      a += ((float)meta->cnt[e]/(float)TT) * (meta->psum[e]/(float)TT);
    aux_out[0] = (float)NE * 0.01f * a;
  }
  int t = blockIdx.x*blockDim.x + threadIdx.x;
  if (t >= TT) return;
  for (int k=0;k<2;++k) {
    int e = tke[2*t+k];
    int pos = atomicAdd(&meta->cursor[e], 1);
    int slot = seg[e] + pos;
    perm[slot]   = t;
    tslot[2*t+k] = slot;
  }
}

// ---- BK=64 staging with free XOR chunk-swizzle (round-4, conflict-free) ----
// ---- round-5: L2-locality block swizzle: XCD-chunked 1D grid + m-bands ----
// ---- round-10: Wd-cvt merged into scatter launch (one fewer serial pass) ----

// fused gate+up+SwiGLU: act[slot, I] = silu(Xg) * Xu  (bf16)
__launch_bounds__(256, 2)
__global__ void k_gemm1(const u16* __restrict__ xh, const u16* __restrict__ wgh, const u16* __restrict__ wuh,
                        const int* __restrict__ perm, const Meta* __restrict__ meta, u16* __restrict__ act) {
  __shared__ u16 As[BM*BK], Gs[BM*BK], Us[BM*BK];
  // bijective remap: bid -> (mt, nt). XCD chunk (2992=8*374), then bands of
  // 8 m-tiles * 22 n-tiles (=176; 17 bands). Band A (2MB) stays in the
  // XCD's 4MB L2 across all 22 n-sweeps.
  int bid = blockIdx.x;
  int wg  = (bid&7)*(G1/8) + (bid>>3);
  int band = wg/176, r = wg%176;
  int mt = band*8 + (r&7);
  int m0 = mt*BM;
  int n0 = (r>>3)*BM;
  int total = meta->seg[NE];
  if (m0 >= total) return;
  int e = 0;
  #pragma unroll
  for (int i=1;i<NE;++i) if (m0 >= meta->seg[i]) e = i;
  int tid = threadIdx.x;
  int srow = tid>>3;                       // 0..31
  int scol = ((tid&7) ^ (srow&7)) * 8;     // swizzled 16B chunk (u16 elems)
  const u16* zp = meta->zeros;
  int tok[4];
  const u16* ap[4]; const u16* gp[4]; const u16* up[4];
  #pragma unroll
  for (int j=0;j<4;++j) {
    tok[j] = perm[m0 + srow + 32*j];
    ap[j]  = xh + (size_t)(tok[j]<0?0:tok[j])*HD + scol;
    size_t rr = (size_t)e*ID + n0 + srow + 32*j;
    gp[j]  = wgh + rr*HD + scol;
    up[j]  = wuh + rr*HD + scol;
  }
  u16* lA = As + tid*8; u16* lG = Gs + tid*8; u16* lU = Us + tid*8;
  int wv = tid>>6, ln = tid&63;
  int wr = (wv>>1)*64, wc = (wv&1)*64;
  int lr = ln&15, kq = ln>>4;
  int kx = lr&7;                           // read-side chunk XOR
  f32x4 accg[4][4] = {};
  f32x4 accu[4][4] = {};
  for (int k0 = 0; k0 < HD; k0 += BK) {
    #pragma unroll
    for (int j=0;j<4;++j) {
      gll16(tok[j]<0 ? (const void*)zp : (const void*)(ap[j]+k0), lA + j*2048);
      gll16(gp[j]+k0, lG + j*2048);
      gll16(up[j]+k0, lU + j*2048);
    }
    __syncthreads();
    #pragma unroll
    for (int h=0; h<2; ++h) {
      int koff = ((h*4 + kq) ^ kx) * 8;
      bf16x8 af[4], gf[4], uf[4];
      #pragma unroll
      for (int m=0;m<4;++m) af[m] = *(const bf16x8*)&As[(wr+m*16+lr)*BK + koff];
      #pragma unroll
      for (int n=0;n<4;++n) {
        gf[n] = *(const bf16x8*)&Gs[(wc+n*16+lr)*BK + koff];
        uf[n] = *(const bf16x8*)&Us[(wc+n*16+lr)*BK + koff];
      }
      #pragma unroll
      for (int m=0;m<4;++m)
        #pragma unroll
        for (int n=0;n<4;++n) {
          accg[m][n] = __builtin_amdgcn_mfma_f32_16x16x32_bf16(af[m], gf[n], accg[m][n], 0,0,0);
          accu[m][n] = __builtin_amdgcn_mfma_f32_16x16x32_bf16(af[m], uf[n], accu[m][n], 0,0,0);
        }
    }
    __syncthreads();
  }
  int rb = wr + (ln>>4)*4;
  int cb = n0 + wc + (ln&15);
  #pragma unroll
  for (int m=0;m<4;++m)
    #pragma unroll
    for (int j=0;j<4;++j) {
      size_t row = (size_t)(m0 + rb + m*16 + j);
      u16* ap2 = act + row*ID + cb;
      #pragma unroll
      for (int n=0;n<4;++n) {
        float g2 = accg[m][n][j], u = accu[m][n][j];
        float sv = g2 / (1.f + __expf(-g2));
        ap2[n*16] = f2bf(sv*u);
      }
    }
}

// down proj, single-N + K-split-2: y[kh][slot, n0..n0+127] partial over half of K.
// 64 acc AGPRs + ~104 VGPR -> 3 waves/SIMD -> 3 blocks/CU -> slots=768,
// grid 2176 -> 2.83 -> 3 rounds -> 94.4% utilization.
__launch_bounds__(256, 3)
__global__ void k_gemm2(const u16* __restrict__ act, const u16* __restrict__ wdh,
                        const Meta* __restrict__ meta, u16* __restrict__ y) {
  __shared__ u16 As[BM*BK], Bs[BM*BK];
  int bid = blockIdx.x;
  int wg  = (bid&7)*(G2/8) + (bid>>3);
  int kh  = (wg >= G2/2) ? 1 : 0;
  int w2  = wg - kh*(G2/2);
  int band = w2>>6, r = w2&63;
  int mt = band*8 + (r&7);
  int m0 = mt*BM;
  int n0 = (r>>3)*BM;
  int total = meta->seg[NE];
  if (m0 >= total) return;
  int e = 0;
  #pragma unroll
  for (int i=1;i<NE;++i) if (m0 >= meta->seg[i]) e = i;
  int kbase = kh * (ID/2);
  u16* yh = y + (size_t)kh*MAXSLOT*HD;
  int tid = threadIdx.x;
  int srow = tid>>3;
  int scol = ((tid&7) ^ (srow&7)) * 8;
  const u16* ab = act + (size_t)(m0 + srow)*ID + kbase + scol;
  const u16* b0 = wdh + ((size_t)e*HD + n0 + srow)*ID + kbase + scol;
  u16* lA = As + tid*8; u16* lB = Bs + tid*8;
  int wv = tid>>6, ln = tid&63;
  int wr = (wv>>1)*64, wc = (wv&1)*64;
  int lr = ln&15, kq = ln>>4;
  int kx = lr&7;
  f32x4 acc[4][4] = {};
  for (int k0 = 0; k0 < ID/2; k0 += BK) {
    #pragma unroll
    for (int j=0;j<4;++j) {
      gll16(ab + (size_t)j*32*ID + k0, lA + j*2048);
      gll16(b0 + (size_t)j*32*ID + k0, lB + j*2048);
    }
    __syncthreads();
    #pragma unroll
    for (int h=0; h<2; ++h) {
      int koff = ((h*4 + kq) ^ kx) * 8;
      bf16x8 af[4], bf[4];
      #pragma unroll
      for (int m=0;m<4;++m) af[m] = *(const bf16x8*)&As[(wr+m*16+lr)*BK + koff];
      #pragma unroll
      for (int n=0;n<4;++n) bf[n] = *(const bf16x8*)&Bs[(wc+n*16+lr)*BK + koff];
      #pragma unroll
      for (int m=0;m<4;++m)
        #pragma unroll
        for (int n=0;n<4;++n)
          acc[m][n] = __builtin_amdgcn_mfma_f32_16x16x32_bf16(af[m], bf[n], acc[m][n], 0,0,0);
    }
    __syncthreads();
  }
  int rb = wr + (ln>>4)*4;
  int cb = n0 + wc + (ln&15);
  #pragma unroll
  for (int m=0;m<4;++m)
    #pragma unroll
    for (int j=0;j<4;++j) {
      u16* yp = yh + (size_t)(m0 + rb + m*16 + j)*HD + cb;
      #pragma unroll
      for (int n=0;n<4;++n) yp[n*16] = f2bf(acc[m][n][j]);
    }
}

// out[t] = w0*(y0[s0]+y1[s0]) + w1*(y0[s1]+y1[s1])
__global__ void k_combine(const u16* __restrict__ y, const int* __restrict__ tslot,
                          const float* __restrict__ tkw, float* __restrict__ out) {
  int idx = blockIdx.x*blockDim.x + threadIdx.x;   // one per 8 elems of out
  int t = idx >> 7;                                // HD/8 = 128 chunks per row
  int c = (idx & 127) * 8;
  int s0 = tslot[2*t], s1 = tslot[2*t+1];
  float w0 = tkw[2*t], w1 = tkw[2*t+1];
  const size_t H2 = (size_t)MAXSLOT*HD;
  union { uint4 v; u16 h[8]; } a0, a1, b0, b1;
  a0.v = *(const uint4*)(y + (size_t)s0*HD + c);
  a1.v = *(const uint4*)(y + H2 + (size_t)s0*HD + c);
  b0.v = *(const uint4*)(y + (size_t)s1*HD + c);
  b1.v = *(const uint4*)(y + H2 + (size_t)s1*HD + c);
  float r[8];
  #pragma unroll
  for (int i=0;i<8;++i)
    r[i] = w0*(bf2f(a0.h[i]) + bf2f(a1.h[i])) + w1*(bf2f(b0.h[i]) + bf2f(b1.h[i]));
  float4 o0 = {r[0],r[1],r[2],r[3]}, o1 = {r[4],r[5],r[6],r[7]};
  float4* op = (float4*)(out + (size_t)t*HD + c);
  op[0] = o0; op[1] = o1;
}

extern "C" void kernel_launch(void* const* d_in, const int* in_sizes, int n_in,
                              void* d_out, int out_size, void* d_ws, size_t ws_size,
                              hipStream_t stream) {
  if (ws_size < WS_NEED) return;   // diagnostic: error would stay at poison signature
  const float* x  = (const float*)d_in[0];
  const float* gw = (const float*)d_in[1];
  const float* Wg = (const float*)d_in[2];
  const float* Wu = (const float*)d_in[3];
  const float* Wd = (const float*)d_in[4];
  float* out = (float*)d_out;
  char* ws = (char*)d_ws;
  u16* xh   = (u16*)(ws + OFF_XH);
  u16* wgh  = (u16*)(ws + OFF_WGH);
  u16* wuh  = (u16*)(ws + OFF_WUH);
  u16* wdh  = (u16*)(ws + OFF_WDH);
  u16* act  = (u16*)(ws + OFF_ACT);
  int* perm = (int*)(ws + OFF_PERM);
  int* tke  = (int*)(ws + OFF_TID);
  int* tslot= (int*)(ws + OFF_TSLOT);
  float* tkw= (float*)(ws + OFF_TW);
  Meta* meta= (Meta*)(ws + OFF_META);
  u16* y    = (u16*)(ws + OFF_Y);

  k_init   <<<INIT_BLK + INIT_CVT, 256, 0, stream>>>(perm, meta, Wg, Wu, wgh);
  k_router <<<512, 256, 0, stream>>>(x, gw, tke, tkw, xh, meta);
  k_scatter<<<SCAT_BLK + SCAT_CVT, 256, 0, stream>>>(tke, meta, perm, tslot,
                                                     out + (size_t)TT*HD, Wd, wdh);
  k_gemm1  <<<G1, 256, 0, stream>>>(xh, wgh, wuh, perm, meta, act);
  k_gemm2  <<<G2, 256, 0, stream>>>(act, wdh, meta, y);
  k_combine<<<TT*HD/8/256, 256, 0, stream>>>(y, tslot, tkw, out);
}